// Round 13
// baseline (209.742 us; speedup 1.0000x reference)
//
#include <hip/hip_runtime.h>

typedef __attribute__((ext_vector_type(4))) float f32x4;
typedef __attribute__((ext_vector_type(4))) unsigned int u32x4;
typedef __attribute__((ext_vector_type(8))) unsigned short u16x8;
typedef __attribute__((ext_vector_type(8))) __bf16 bf16x8;

#define DEVFN static __device__ __forceinline__

DEVFN unsigned short f2b(float f) {
  unsigned u = __builtin_bit_cast(unsigned, f);
  u += 0x7fffu + ((u >> 16) & 1u);
  return (unsigned short)(u >> 16);
}
DEVFN float b2f(unsigned short h) {
  unsigned u = ((unsigned)h) << 16;
  return __builtin_bit_cast(float, u);
}
DEVFN float sigf(float x) { return 1.0f / (1.0f + __expf(-x)); }

// ---------------- geometry ----------------
#define CS 264
#define KPAD 2432
#define NTILE 38

// ---------------- workspace layout (bytes) ----------------
#define XP_BYTES (16ull*66*66*CS*2)
#define WT_BYTES (512ull*KPAD*2)       // wt: row-major [o][kpad]
#define W2_BYTES (64ull*512*2)
#define CV_BYTES (65536ull*512*2)
#define PS_BYTES (512ull*256*2*4)
#define XP_OFF 0ull
#define WT_OFF (XP_OFF + XP_BYTES)
#define W2_OFF (WT_OFF + WT_BYTES)
#define CV_OFF (W2_OFF + W2_BYTES)
#define PS_OFF (CV_OFF + CV_BYTES)
#define SB_OFF (PS_OFF + PS_BYTES)

#define GLOAD16(gp, lp) __builtin_amdgcn_global_load_lds( \
    (__attribute__((address_space(1))) void*)(gp),        \
    (__attribute__((address_space(3))) void*)(lp), 16, 0, 0)

#define BAR()  do { __builtin_amdgcn_s_barrier(); __builtin_amdgcn_sched_barrier(0); } while (0)
#define WLG0() do { asm volatile("s_waitcnt lgkmcnt(0)" ::: "memory"); __builtin_amdgcn_sched_barrier(0); } while (0)

// ---------------- merged prep kernel (pack_in + border + grid + wt + w2 in ONE launch) ----------------
// [0,8192) pack_in | [8192,8729) zero-border | [8729,8985) grid ch | [8985,13849) conv w (row-major) | [13849,13977) head w
__global__ void k_prep(const float* __restrict__ in1, const float* __restrict__ wc,
                       const float* __restrict__ wl, const float* __restrict__ wm,
                       unsigned short* __restrict__ xp, unsigned short* __restrict__ wt,
                       unsigned short* __restrict__ w2) {
  __shared__ float lt[32][65];
  int bid = blockIdx.x, tid = threadIdx.x;
  if (bid < 8192) {                        // pack_in: interior cells, ch<256
    int cg = bid & 7, y = (bid >> 3) & 63, b = bid >> 9;
    int x = tid & 63, cr = tid >> 6;
#pragma unroll
    for (int i = 0; i < 8; ++i) {
      int cl = i * 4 + cr;
      lt[cl][x] = in1[(((size_t)(b * 256 + cg * 32 + cl) * 64 + y) * 64) + x];
    }
    __syncthreads();
    int xx = tid >> 2, ch = tid & 3;
    u16x8 v;
#pragma unroll
    for (int j = 0; j < 8; ++j) v[j] = f2b(lt[ch * 8 + j][xx]);
    size_t base = ((size_t)((b * 66 + y + 1) * 66 + xx + 1)) * CS + cg * 32 + ch * 8;
    *(u16x8*)(xp + base) = v;
  } else if (bid < 8729) {                 // border cells, all ch
    int idx = (bid - 8192) * 256 + tid;
    if (idx >= 137280) return;
    int cell_i = idx / 33, u = idx - cell_i * 33;
    int b = cell_i / 260, r = cell_i - b * 260;
    int y, x;
    if (r < 66) { y = 0; x = r; }
    else if (r < 132) { y = 65; x = r - 66; }
    else if (r < 196) { y = r - 131; x = 0; }
    else { y = r - 195; x = 65; }
    int cell = (b * 66 + y) * 66 + x;
    *(u32x4*)((unsigned char*)xp + (size_t)cell * (CS * 2) + u * 16) = (u32x4){0u, 0u, 0u, 0u};
  } else if (bid < 8985) {                 // grid channels 256,257 + pad
    int pid = (bid - 8729) * 256 + tid;
    int b = pid >> 12, pi = pid & 4095, y = pi >> 6, x = pi & 63;
    u16x8 v0 = (u16x8){0, 0, 0, 0, 0, 0, 0, 0};
    v0[0] = f2b((float)x); v0[1] = f2b((float)y);
    *(u16x8*)(xp + ((size_t)((b * 66 + y + 1) * 66 + x + 1)) * CS + 256) = v0;
  } else if (bid < 13849) {                // conv weights row-major: wt[o][kpad]
    int idx = (bid - 8985) * 256 + tid;    // 512*2432 = 1245184
    int o = idx / KPAD, k = idx - o * KPAD;
    int dy = k / 800, t = k - dy * 800;
    int dx = t / CS, ci = t - dx * CS;
    float v = (dy < 3 && dx < 3 && ci < 258) ? wc[(size_t)(o * 258 + ci) * 9 + dy * 3 + dx] : 0.f;
    wt[idx] = f2b(v);
  } else {                                 // head weights
    int idx = (bid - 13849) * 256 + tid;
    int o = idx >> 9, k = idx & 511;
    float v = 0.f;
    if (o < 10) v = wl[o * 512 + k];
    else if (o < 58) v = wm[(o - 10) * 512 + k];
    w2[idx] = f2b(v);
  }
}

// ---------------- conv: 256x256 tile, BK=64, rotated 4-window schedule, 3 barriers/tile (R10) ----------------
__global__ __launch_bounds__(512, 2) void k_conv8(const unsigned short* __restrict__ xp,
                                                  const unsigned short* __restrict__ wt,
                                                  unsigned short* __restrict__ cv,
                                                  float* __restrict__ ps) {
  extern __shared__ char smem[];
  int tid = threadIdx.x, lane = tid & 63, wv = tid >> 6;
  int wm = wv >> 2, wn = wv & 3;
  int bid = blockIdx.x;
  int xcd = bid & 7, j = bid >> 3;
  int nt = j & 1;
  int mt = xcd * 32 + (j >> 1);
  int n0 = nt * 256;
  int pix0 = mt * 256;
  int b = pix0 >> 12, pi0 = pix0 & 4095;

  // ---- staging constants ----
  int srow = tid >> 3;
  int ug = (tid & 7) ^ (srow & 7);
  unsigned cellB[4], oB[4];
#pragma unroll
  for (int jj = 0; jj < 4; ++jj) {
    int pi = pi0 + srow + 64 * jj;
    int yy = pi >> 6, xx = pi & 63;
    cellB[jj] = (unsigned)((b * 66 + yy) * 66 + xx) * (CS * 2);
    oB[jj] = (unsigned)(n0 + srow + 64 * jj) * (KPAD * 2);
  }

  auto stageA = [&](int tau, int h) {
    int buf = tau & 1;
    unsigned k = (unsigned)tau * 64u + (unsigned)ug * 8u;
    unsigned dy = k / 800u;
    unsigned t = k - dy * 800u;
    unsigned off = dy * (66u * CS * 2u) + t * 2u;
    const unsigned char* g = (const unsigned char*)xp;
    char* l = smem + buf * 65536 + h * 16384;
    GLOAD16(g + cellB[h * 2] + off, l + tid * 16);
    GLOAD16(g + cellB[h * 2 + 1] + off, l + 8192 + tid * 16);
  };
  auto stageB = [&](int tau, int h) {
    int buf = tau & 1;
    unsigned k2 = ((unsigned)tau * 64u + (unsigned)ug * 8u) * 2u;
    const unsigned char* g = (const unsigned char*)wt;
    char* l = smem + buf * 65536 + 32768 + h * 16384;
    GLOAD16(g + oB[h * 2] + k2, l + tid * 16);
    GLOAD16(g + oB[h * 2 + 1] + k2, l + 8192 + tid * 16);
  };

  // ---- fragment read constants ----
  unsigned aoffb[8], boffb[4];
#pragma unroll
  for (int mf = 0; mf < 8; ++mf) aoffb[mf] = (unsigned)(wm * 128 + mf * 16 + (lane & 15)) * 128u;
#pragma unroll
  for (int nf = 0; nf < 4; ++nf) boffb[nf] = 32768u + (unsigned)(wn * 64 + nf * 16 + (lane & 15)) * 128u;
  int ko = (lane >> 4) & 3, xm = lane & 7;
  unsigned un[2];
#pragma unroll
  for (int kk = 0; kk < 2; ++kk) un[kk] = (unsigned)(((kk * 4 + ko) ^ xm) * 16);

  f32x4 acc[8][4];
#pragma unroll
  for (int i = 0; i < 8; ++i)
#pragma unroll
    for (int jj = 0; jj < 4; ++jj) acc[i][jj] = (f32x4){0.f, 0.f, 0.f, 0.f};

  // ---- prologue: stage tile0 + tile1-B; then pre-read af-lo-k0/bf-k0 of tile0 ----
  stageB(0, 0); stageB(0, 1); stageA(0, 0); stageA(0, 1); stageB(1, 0); stageB(1, 1);
  asm volatile("s_waitcnt vmcnt(4)" ::: "memory");
  __builtin_amdgcn_sched_barrier(0);
  BAR();

  bf16x8 af[4][2], bfr[4][2];
  {
    const char* base0 = smem;
#pragma unroll
    for (int s = 0; s < 4; ++s) af[s][0] = *(const bf16x8*)(base0 + aoffb[s] + un[0]);
#pragma unroll
    for (int s = 0; s < 4; ++s) bfr[s][0] = *(const bf16x8*)(base0 + boffb[s] + un[0]);
  }

#define MM(mi, ni, kk, ab) acc[(ab) + (mi)][(ni)] = \
    __builtin_amdgcn_mfma_f32_16x16x32_bf16(af[(mi)][(kk)], bfr[(ni)][(kk)], acc[(ab) + (mi)][(ni)], 0, 0, 0)

#pragma unroll 1
  for (int tau = 0; tau <= NTILE - 2; ++tau) {   // steady: 0..36
    bool sB = tau < NTILE - 2;
    const char* base = smem + (tau & 1) * 65536;
    const char* nbase = smem + ((tau + 1) & 1) * 65536;
    auto rdA = [&](int s, int kk, int hi) { af[s][kk] = *(const bf16x8*)(base + aoffb[hi * 4 + s] + un[kk]); };
    auto rdB = [&](int s, int kk) { bfr[s][kk] = *(const bf16x8*)(base + boffb[s] + un[kk]); };
    auto rdAn = [&](int s) { af[s][0] = *(const bf16x8*)(nbase + aoffb[s] + un[0]); };
    auto rdBn = [&](int s) { bfr[s][0] = *(const bf16x8*)(nbase + boffb[s] + un[0]); };

    // ---- W0: MFMA m-lo x k0; hide {af-lo-k1, bf-k1}; stageA(+1,0); BAR
    WLG0();
    __builtin_amdgcn_s_setprio(1);
    MM(0, 0, 0, 0); MM(0, 1, 0, 0); rdA(0, 1, 0);
    MM(0, 2, 0, 0); MM(0, 3, 0, 0); rdA(1, 1, 0);
    MM(1, 0, 0, 0); MM(1, 1, 0, 0); rdA(2, 1, 0);
    MM(1, 2, 0, 0); MM(1, 3, 0, 0); rdA(3, 1, 0);
    MM(2, 0, 0, 0); MM(2, 1, 0, 0); rdB(0, 1);
    MM(2, 2, 0, 0); MM(2, 3, 0, 0); rdB(1, 1);
    MM(3, 0, 0, 0); MM(3, 1, 0, 0); rdB(2, 1);
    MM(3, 2, 0, 0); MM(3, 3, 0, 0); rdB(3, 1);
    __builtin_amdgcn_s_setprio(0);
    stageA(tau + 1, 0);
    BAR();

    // ---- W1: MFMA m-lo x k1; hide {af-hi-k0}; stageA(+1,1); BAR
    WLG0();
    __builtin_amdgcn_s_setprio(1);
    MM(0, 0, 1, 0); MM(0, 1, 1, 0); MM(0, 2, 1, 0); MM(0, 3, 1, 0); rdA(0, 0, 1);
    MM(1, 0, 1, 0); MM(1, 1, 1, 0); MM(1, 2, 1, 0); MM(1, 3, 1, 0); rdA(1, 0, 1);
    MM(2, 0, 1, 0); MM(2, 1, 1, 0); MM(2, 2, 1, 0); MM(2, 3, 1, 0); rdA(2, 0, 1);
    MM(3, 0, 1, 0); MM(3, 1, 1, 0); MM(3, 2, 1, 0); MM(3, 3, 1, 0); rdA(3, 0, 1);
    __builtin_amdgcn_s_setprio(0);
    stageA(tau + 1, 1);
    BAR();

    // ---- W2: MFMA m-hi x k0; hide {af-hi-k1}; drain; stageB(+2)/vmcnt; BAR
    WLG0();
    __builtin_amdgcn_s_setprio(1);
    MM(0, 0, 0, 4); MM(0, 1, 0, 4); MM(0, 2, 0, 4); MM(0, 3, 0, 4); rdA(0, 1, 1);
    MM(1, 0, 0, 4); MM(1, 1, 0, 4); MM(1, 2, 0, 4); MM(1, 3, 0, 4); rdA(1, 1, 1);
    MM(2, 0, 0, 4); MM(2, 1, 0, 4); MM(2, 2, 0, 4); MM(2, 3, 0, 4); rdA(2, 1, 1);
    MM(3, 0, 0, 4); MM(3, 1, 0, 4); MM(3, 2, 0, 4); MM(3, 3, 0, 4); rdA(3, 1, 1);
    __builtin_amdgcn_s_setprio(0);
    WLG0();
    if (sB) {
      stageB(tau + 2, 0); stageB(tau + 2, 1);
      asm volatile("s_waitcnt vmcnt(4)" ::: "memory");
      __builtin_amdgcn_sched_barrier(0);
    } else {
      asm volatile("s_waitcnt vmcnt(0)" ::: "memory");
      __builtin_amdgcn_sched_barrier(0);
    }
    BAR();

    // ---- W3: MFMA m-hi x k1; hide NEXT-tile {af-lo-k0, bf-k0} (unconditional); no barrier
    __builtin_amdgcn_s_setprio(1);
    MM(0, 0, 1, 4); MM(0, 1, 1, 4); rdAn(0);
    MM(0, 2, 1, 4); MM(0, 3, 1, 4); rdAn(1);
    MM(1, 0, 1, 4); MM(1, 1, 1, 4); rdAn(2);
    MM(1, 2, 1, 4); MM(1, 3, 1, 4); rdAn(3);
    MM(2, 0, 1, 4); MM(2, 1, 1, 4); rdBn(0);
    MM(2, 2, 1, 4); MM(2, 3, 1, 4); rdBn(1);
    MM(3, 0, 1, 4); MM(3, 1, 1, 4); rdBn(2);
    MM(3, 2, 1, 4); MM(3, 3, 1, 4); rdBn(3);
    __builtin_amdgcn_s_setprio(0);
  }

  // ---- peeled last tile (tau = 37, buf1): no staging, no barriers ----
  {
    const char* base = smem + 65536;
    auto rdA = [&](int s, int kk, int hi) { af[s][kk] = *(const bf16x8*)(base + aoffb[hi * 4 + s] + un[kk]); };
    auto rdB = [&](int s, int kk) { bfr[s][kk] = *(const bf16x8*)(base + boffb[s] + un[kk]); };
    WLG0();
    MM(0, 0, 0, 0); MM(0, 1, 0, 0); rdA(0, 1, 0);
    MM(0, 2, 0, 0); MM(0, 3, 0, 0); rdA(1, 1, 0);
    MM(1, 0, 0, 0); MM(1, 1, 0, 0); rdA(2, 1, 0);
    MM(1, 2, 0, 0); MM(1, 3, 0, 0); rdA(3, 1, 0);
    MM(2, 0, 0, 0); MM(2, 1, 0, 0); rdB(0, 1);
    MM(2, 2, 0, 0); MM(2, 3, 0, 0); rdB(1, 1);
    MM(3, 0, 0, 0); MM(3, 1, 0, 0); rdB(2, 1);
    MM(3, 2, 0, 0); MM(3, 3, 0, 0); rdB(3, 1);
    WLG0();
    MM(0, 0, 1, 0); MM(0, 1, 1, 0); MM(0, 2, 1, 0); MM(0, 3, 1, 0); rdA(0, 0, 1);
    MM(1, 0, 1, 0); MM(1, 1, 1, 0); MM(1, 2, 1, 0); MM(1, 3, 1, 0); rdA(1, 0, 1);
    MM(2, 0, 1, 0); MM(2, 1, 1, 0); MM(2, 2, 1, 0); MM(2, 3, 1, 0); rdA(2, 0, 1);
    MM(3, 0, 1, 0); MM(3, 1, 1, 0); MM(3, 2, 1, 0); MM(3, 3, 1, 0); rdA(3, 0, 1);
    WLG0();
    MM(0, 0, 0, 4); MM(0, 1, 0, 4); MM(0, 2, 0, 4); MM(0, 3, 0, 4); rdA(0, 1, 1);
    MM(1, 0, 0, 4); MM(1, 1, 0, 4); MM(1, 2, 0, 4); MM(1, 3, 0, 4); rdA(1, 1, 1);
    MM(2, 0, 0, 4); MM(2, 1, 0, 4); MM(2, 2, 0, 4); MM(2, 3, 0, 4); rdA(2, 1, 1);
    MM(3, 0, 0, 4); MM(3, 1, 0, 4); MM(3, 2, 0, 4); MM(3, 3, 0, 4); rdA(3, 1, 1);
    WLG0();
    MM(0, 0, 1, 4); MM(0, 1, 1, 4); MM(0, 2, 1, 4); MM(0, 3, 1, 4);
    MM(1, 0, 1, 4); MM(1, 1, 1, 4); MM(1, 2, 1, 4); MM(1, 3, 1, 4);
    MM(2, 0, 1, 4); MM(2, 1, 1, 4); MM(2, 2, 1, 4); MM(2, 3, 1, 4);
    MM(3, 0, 1, 4); MM(3, 1, 1, 4); MM(3, 2, 1, 4); MM(3, 3, 1, 4);
  }
#undef MM

  __syncthreads();  // all waves done before epilogue overwrites smem

  // ---- epilogue 1: raw conv -> cv (bf16), via LDS repack (XOR-4 store swizzle) ----
  unsigned short* l16 = (unsigned short*)smem;
#pragma unroll
  for (int mf = 0; mf < 8; ++mf)
#pragma unroll
    for (int nf = 0; nf < 4; ++nf)
#pragma unroll
      for (int r = 0; r < 4; ++r) {
        int row = wm * 128 + mf * 16 + (lane >> 4) * 4 + r;
        int col = wn * 64 + nf * 16 + (lane & 15);
        int colx = col ^ (((row >> 2) & 3) << 3);
        l16[row * 256 + colx] = f2b(acc[mf][nf][r]);
      }
  __syncthreads();
#pragma unroll
  for (int i = 0; i < 16; ++i) {
    int q = tid + 512 * i;
    int prow = q >> 5, c16 = q & 31;
    int c16g = c16 ^ ((prow >> 2) & 3);
    *(u16x8*)(cv + ((size_t)(pix0 + prow) * 512 + n0 + c16g * 8)) = *(const u16x8*)(l16 + q * 8);
  }
  __syncthreads();

  // ---- epilogue 2: BN partial stats from f32 acc ----
  float* lf = (float*)smem;
  float sv[4], qv[4];
#pragma unroll
  for (int nf = 0; nf < 4; ++nf) {
    float s = 0.f, q = 0.f;
#pragma unroll
    for (int mf = 0; mf < 8; ++mf)
#pragma unroll
      for (int r = 0; r < 4; ++r) { float v = acc[mf][nf][r]; s += v; q += v * v; }
    s += __shfl_xor(s, 16); s += __shfl_xor(s, 32);
    q += __shfl_xor(q, 16); q += __shfl_xor(q, 32);
    sv[nf] = s; qv[nf] = q;
  }
  if (lane < 16) {
#pragma unroll
    for (int nf = 0; nf < 4; ++nf) {
      int ch = wn * 64 + nf * 16 + lane;
      lf[wm * 256 + ch] = sv[nf];
      lf[512 + wm * 256 + ch] = qv[nf];
    }
  }
  __syncthreads();
  if (tid < 256) {
    float S = lf[tid] + lf[256 + tid];
    float Q = lf[512 + tid] + lf[768 + tid];
    ((float2*)ps)[(size_t)(n0 + tid) * 256 + mt] = make_float2(S, Q);
  }
}

// ---------------- BN finalize: scale/bias (16 blocks, shfl-reduced) ----------------
__global__ void k_bnfinal(const float* __restrict__ ps, const float* __restrict__ gamma,
                          const float* __restrict__ beta, float* __restrict__ sb) {
  int c = blockIdx.x * 32 + (threadIdx.x >> 3);
  int sl = threadIdx.x & 7;
  const float2* p2 = (const float2*)ps + (size_t)c * 256 + sl * 32;
  float s = 0.f, q = 0.f;
#pragma unroll 8
  for (int i = 0; i < 32; ++i) { float2 v = p2[i]; s += v.x; q += v.y; }
  s += __shfl_xor(s, 1); s += __shfl_xor(s, 2); s += __shfl_xor(s, 4);
  q += __shfl_xor(q, 1); q += __shfl_xor(q, 2); q += __shfl_xor(q, 4);
  if (sl == 0) {
    float mean = s * (1.0f / 65536.0f);
    float var = q * (1.0f / 65536.0f) - mean * mean;
    float sc = gamma[c] / sqrtf(var + 1e-5f);
    sb[c] = sc;
    sb[512 + c] = beta[c] - mean * sc;
  }
}

// ---------------- head: 512 blocks x 128 px (2 blocks/CU, 8 waves/CU) ----------------
// GEMM: 4 waves x 32 rows (acc[2][4]), K=512, BN+leaky fused on A-load; decode on tid<128.
__global__ __launch_bounds__(256) void k_head(const unsigned short* __restrict__ cv,
                                              const unsigned short* __restrict__ w2,
                                              const float* __restrict__ bl,
                                              const float* __restrict__ bm,
                                              const float* __restrict__ sb,
                                              float* __restrict__ out) {
  __shared__ float lo[128][59];
  __shared__ float sS[512], sBb[512];
  int tid = threadIdx.x, lane = tid & 63, wv = tid >> 6;
  int pix0 = blockIdx.x * 128;
  sS[tid] = sb[tid]; sS[256 + tid] = sb[256 + tid];
  sBb[tid] = sb[512 + tid]; sBb[256 + tid] = sb[768 + tid];
  __syncthreads();

  f32x4 acc[2][4];
#pragma unroll
  for (int mf = 0; mf < 2; ++mf)
#pragma unroll
    for (int nf = 0; nf < 4; ++nf) acc[mf][nf] = (f32x4){0.f, 0.f, 0.f, 0.f};
  int ko = lane >> 4;

  for (int k0 = 0; k0 < 512; k0 += 32) {
    int c0 = k0 + ko * 8;
    f32x4 sc0 = *(const f32x4*)&sS[c0], sc1 = *(const f32x4*)&sS[c0 + 4];
    f32x4 bo0 = *(const f32x4*)&sBb[c0], bo1 = *(const f32x4*)&sBb[c0 + 4];
    bf16x8 bg[4];
#pragma unroll
    for (int f = 0; f < 4; ++f)
      bg[f] = *(const bf16x8*)(w2 + (size_t)(f * 16 + (lane & 15)) * 512 + c0);
    bf16x8 a[2];
#pragma unroll
    for (int f = 0; f < 2; ++f) {
      u16x8 raw = *(const u16x8*)(cv + (size_t)(pix0 + wv * 32 + f * 16 + (lane & 15)) * 512 + c0);
      u16x8 av;
#pragma unroll
      for (int jj = 0; jj < 4; ++jj) {
        float v = b2f(raw[jj]) * sc0[jj] + bo0[jj];
        v = (v > 0.f) ? v : 0.1f * v;
        av[jj] = f2b(v);
      }
#pragma unroll
      for (int jj = 0; jj < 4; ++jj) {
        float v = b2f(raw[4 + jj]) * sc1[jj] + bo1[jj];
        v = (v > 0.f) ? v : 0.1f * v;
        av[4 + jj] = f2b(v);
      }
      a[f] = __builtin_bit_cast(bf16x8, av);
    }
#pragma unroll
    for (int mf = 0; mf < 2; ++mf)
#pragma unroll
      for (int nf = 0; nf < 4; ++nf)
        acc[mf][nf] = __builtin_amdgcn_mfma_f32_16x16x32_bf16(a[mf], bg[nf], acc[mf][nf], 0, 0, 0);
  }

  float bias[4]; int colv[4];
#pragma unroll
  for (int nf = 0; nf < 4; ++nf) {
    int col = nf * 16 + (lane & 15);
    colv[nf] = col;
    bias[nf] = (col < 10) ? bl[col] : ((col < 58) ? bm[col - 10] : 0.f);
  }
#pragma unroll
  for (int mf = 0; mf < 2; ++mf)
#pragma unroll
    for (int nf = 0; nf < 4; ++nf)
#pragma unroll
      for (int r = 0; r < 4; ++r) {
        int row = wv * 32 + mf * 16 + (lane >> 4) * 4 + r;
        if (colv[nf] < 58) lo[row][colv[nf]] = acc[mf][nf][r] + bias[nf];
      }
  __syncthreads();

  // ---- decode: one thread = one pixel (tid < 128) ----
  if (tid < 128) {
    int pix = pix0 + tid;
    int b = pix >> 12, pi = pix & 4095;
    int yi = pi >> 6, xi = pi & 63;
    float X = (float)xi, Y = (float)yi;
    const float* O = lo[tid];

    float* outP = out;
    float* outB = out + 655360;
    float* outOL = out + 1572864;
    float* outOC = out + 2752512;
    float* outML = out + 3932160;
    float* outMC = out + 4521984;
    float* outWC = out + 5111808;
    float* outOD = out + 5636096;

    float pr[10];
#pragma unroll
    for (int i = 0; i < 10; ++i) { pr[i] = O[i]; outP[(size_t)pix * 10 + i] = pr[i]; }
    const float st = 8.f, ist = 0.125f;
    float l0 = pr[0] * pr[0] * st, l1 = pr[1] * pr[1] * st;
    float l2 = pr[2] * pr[2] * st, l3 = pr[3] * pr[3] * st;
    float cx = X * st + 4.f, cy = Y * st + 4.f;
    float xmin = cx - l3, ymin = cy - l0, xmax = cx + l1, ymax = cy + l2;
    float w = l1 + l3, h = l0 + l2;
    float xc = 0.5f * (xmax + xmin), yc = 0.5f * (ymax + ymin);
    float r = sigf(pr[8]);
    float maskr = (r > 0.9f) ? 0.f : 1.f;
    float s0 = sigf(pr[4]) * maskr, s1 = sigf(pr[5]) * maskr;
    float s2 = sigf(pr[6]) * maskr, s3 = sigf(pr[7]) * maskr;
    float conf = sigf(pr[9]);
    {
      size_t bo = (size_t)pix * 14;
      outB[bo + 0] = xc; outB[bo + 1] = yc; outB[bo + 2] = w; outB[bo + 3] = h;
      outB[bo + 4] = s0; outB[bo + 5] = s1; outB[bo + 6] = s2; outB[bo + 7] = s3;
      outB[bo + 8] = r;  outB[bo + 9] = l0; outB[bo + 10] = l1; outB[bo + 11] = l2;
      outB[bo + 12] = l3; outB[bo + 13] = conf;
    }
    float x1 = xmin + s0 * w, x7 = xmax - s2 * w;
    float y5 = ymin + s1 * h, y3 = ymax - s3 * h;
    float xob = 0.5f * (x1 + x7), yob = 0.5f * (y5 + y3);
    float ov[22];
#pragma unroll
    for (int jj = 0; jj < 22; ++jj) ov[jj] = sigf(O[28 + jj]);
    float eps = ceilf(0.01f * w);
    bool c0 = x1 < xmin + eps;
    float xp0 = c0 ? x1 : xmin + ov[0] * (x1 - xmin);
    float yp0 = c0 ? ymin + ov[0] * (y3 - ymin)
                   : (y3 - ymin) / (xmin - x1 + 1e-8f) * (xp0 - x1) + ymin;
    bool c2 = x1 > xmax - eps;
    float xp2 = c2 ? x1 : xmax - ov[1] * (xmax - x1);
    float yp2 = c2 ? ymin + ov[1] * (y5 - ymin)
                   : (y5 - ymin) / (xmax - x1 + 1e-8f) * (xp2 - x1) + ymin;
    bool c6 = x7 < xmin + eps;
    float xp6 = c6 ? x7 : xmin + ov[2] * (x7 - xmin);
    float yp6 = c6 ? ymax - ov[2] * (ymax - y3)
                   : (y3 - ymax) / (xmin - x7 + 1e-8f) * (xp6 - x7) + ymax;
    bool c8c = x7 > xmax - eps;
    float xp8 = c8c ? x7 : xmax - ov[3] * (xmax - x7);
    float yp8 = c8c ? ymax - ov[3] * (ymax - y5)
                    : (y5 - ymax) / (xmax - x7 + 1e-8f) * (xp8 - x7) + ymax;

    size_t olb = ((size_t)b * 18) * 4096 + pi;
    outOL[olb + 0 * 4096] = yp0 * ist + 1.f - Y;
    outOL[olb + 1 * 4096] = xp0 * ist + 1.f - X;
    outOL[olb + 2 * 4096] = ymin * ist + 1.f - Y;
    outOL[olb + 3 * 4096] = x1 * ist - X;
    outOL[olb + 4 * 4096] = yp2 * ist + 1.f - Y;
    outOL[olb + 5 * 4096] = xp2 * ist - 1.f - X;
    outOL[olb + 6 * 4096] = y3 * ist - Y;
    outOL[olb + 7 * 4096] = xmin * ist + 1.f - X;
    outOL[olb + 8 * 4096] = 0.f;
    outOL[olb + 9 * 4096] = 0.f;
    outOL[olb + 10 * 4096] = y5 * ist - Y;
    outOL[olb + 11 * 4096] = xmax * ist - 1.f - X;
    outOL[olb + 12 * 4096] = yp6 * ist - 1.f - Y;
    outOL[olb + 13 * 4096] = xp6 * ist + 1.f - X;
    outOL[olb + 14 * 4096] = ymax * ist - 1.f - Y;
    outOL[olb + 15 * 4096] = x7 * ist - X;
    outOL[olb + 16 * 4096] = yp8 * ist - 1.f - Y;
    outOL[olb + 17 * 4096] = xp8 * ist - 1.f - X;

    float A1 = x1 - xmax, B1 = ymin - y5, A2 = xmin - x7, B2 = y3 - ymax;
    float width = 0.5f * (sqrtf(A1 * A1 + B1 * B1) + sqrtf(A2 * A2 + B2 * B2));
    float C1 = xmin - x1, D1 = y3 - ymin, C2 = x7 - xmax, D2 = ymax - y5;
    float height = 0.5f * (sqrtf(C1 * C1 + D1 * D1) + sqrtf(C2 * C2 + D2 * D2));
    float ang = 0.5f * (atanf((y5 - ymin) / (xmax - x1 + 1e-4f)) +
                        atanf((ymax - y3) / (x7 - xmin + 1e-4f)));
    float ca = cosf(ang), sa = sinf(ang);
    const float DD = 0.70710678118654752f;
    const float dyc[9] = {DD, 1.f, DD, 0.f, 0.f, 0.f, -DD, -1.f, -DD};
    const float dxc[9] = {DD, 0.f, -DD, 1.f, 0.f, -1.f, DD, 0.f, -DD};
    size_t ocb = ((size_t)b * 18) * 4096 + pi;
    size_t odb = (size_t)pix * 18;
#pragma unroll
    for (int k = 0; k < 9; ++k) {
      float xd = xob - 0.5f * width + ov[13 + k] * width;
      float yd = yob - 0.5f * height + ov[4 + k] * height;
      float ddx = xd - xob, ddy = yd - yob;
      float xd0 = ca * ddx - sa * ddy + xob;
      float xdc = fminf(fmaxf(xd0, xmin), xmax);
      float yd0 = sa * ddx + ca * ddy + yob;
      float ydc = fminf(fmaxf(yd0, ymin), ymax);
      outOC[ocb + (size_t)(2 * k) * 4096] = ydc * ist + dyc[k] - Y;
      outOC[ocb + (size_t)(2 * k + 1) * 4096] = xdc * ist + dxc[k] - X;
      outOD[odb + k] = xdc;
      outOD[odb + 9 + k] = ydc;
    }
    size_t mlb = ((size_t)b * 9) * 4096 + pi;
#pragma unroll
    for (int k = 0; k < 9; ++k) outML[mlb + (size_t)k * 4096] = sigf(O[10 + k]);
#pragma unroll
    for (int k = 0; k < 9; ++k) outMC[mlb + (size_t)k * 4096] = sigf(O[19 + k]);
    float v8[8], mx = -1e30f;
#pragma unroll
    for (int k = 0; k < 8; ++k) { v8[k] = O[50 + k]; mx = fmaxf(mx, v8[k]); }
    float sm = 0.f;
#pragma unroll
    for (int k = 0; k < 8; ++k) { v8[k] = __expf(v8[k] - mx); sm += v8[k]; }
    float inv = 1.f / sm;
    size_t wcb = ((size_t)b * 8) * 4096 + pi;
#pragma unroll
    for (int k = 0; k < 8; ++k) outWC[wcb + (size_t)k * 4096] = v8[k] * inv;
  }
}

// ---------------- launch ----------------
extern "C" void kernel_launch(void* const* d_in, const int* in_sizes, int n_in,
                              void* d_out, int out_size, void* d_ws, size_t ws_size,
                              hipStream_t stream) {
  const float* in1 = (const float*)d_in[0];
  const float* wconv = (const float*)d_in[1];
  const float* gamma = (const float*)d_in[2];
  const float* beta = (const float*)d_in[3];
  const float* wloc = (const float*)d_in[4];
  const float* bloc = (const float*)d_in[5];
  const float* wmask = (const float*)d_in[6];
  const float* bmask = (const float*)d_in[7];
  unsigned char* ws = (unsigned char*)d_ws;
  unsigned short* xp = (unsigned short*)(ws + XP_OFF);
  unsigned short* wt = (unsigned short*)(ws + WT_OFF);
  unsigned short* w2 = (unsigned short*)(ws + W2_OFF);
  unsigned short* cv = (unsigned short*)(ws + CV_OFF);
  float* ps = (float*)(ws + PS_OFF);
  float* sb = (float*)(ws + SB_OFF);
  float* out = (float*)d_out;

  (void)hipFuncSetAttribute(reinterpret_cast<const void*>(k_conv8),
                            hipFuncAttributeMaxDynamicSharedMemorySize, 131072);

  k_prep<<<dim3(13977), dim3(256), 0, stream>>>(in1, wconv, wloc, wmask, xp, wt, w2);
  k_conv8<<<dim3(512), dim3(512), 131072, stream>>>(xp, wt, cv, ps);
  k_bnfinal<<<dim3(16), dim3(256), 0, stream>>>(ps, gamma, beta, sb);
  k_head<<<dim3(512), dim3(256), 0, stream>>>(cv, w2, bloc, bmask, sb, out);
}

// Round 14
// 203.597 us; speedup vs baseline: 1.0302x; 1.0302x over previous
//
#include <hip/hip_runtime.h>

typedef __attribute__((ext_vector_type(4))) float f32x4;
typedef __attribute__((ext_vector_type(4))) unsigned int u32x4;
typedef __attribute__((ext_vector_type(8))) unsigned short u16x8;
typedef __attribute__((ext_vector_type(8))) __bf16 bf16x8;

#define DEVFN static __device__ __forceinline__

DEVFN unsigned short f2b(float f) {
  unsigned u = __builtin_bit_cast(unsigned, f);
  u += 0x7fffu + ((u >> 16) & 1u);
  return (unsigned short)(u >> 16);
}
DEVFN float b2f(unsigned short h) {
  unsigned u = ((unsigned)h) << 16;
  return __builtin_bit_cast(float, u);
}
DEVFN float sigf(float x) { return 1.0f / (1.0f + __expf(-x)); }

// ---------------- geometry ----------------
#define CS 264
#define KPAD 2432
#define NTILE 38

// ---------------- workspace layout (bytes) ----------------
#define XP_BYTES (16ull*66*66*CS*2)
#define WT_BYTES (512ull*KPAD*2)       // wt: row-major [o][kpad]
#define W2_BYTES (64ull*512*2)
#define CV_BYTES (65536ull*512*2)
#define PS_BYTES (512ull*256*2*4)
#define XP_OFF 0ull
#define WT_OFF (XP_OFF + XP_BYTES)
#define W2_OFF (WT_OFF + WT_BYTES)
#define CV_OFF (W2_OFF + W2_BYTES)
#define PS_OFF (CV_OFF + CV_BYTES)
#define SB_OFF (PS_OFF + PS_BYTES)

#define GLOAD16(gp, lp) __builtin_amdgcn_global_load_lds( \
    (__attribute__((address_space(1))) void*)(gp),        \
    (__attribute__((address_space(3))) void*)(lp), 16, 0, 0)

#define BAR()  do { __builtin_amdgcn_s_barrier(); __builtin_amdgcn_sched_barrier(0); } while (0)
#define WLG0() do { asm volatile("s_waitcnt lgkmcnt(0)" ::: "memory"); __builtin_amdgcn_sched_barrier(0); } while (0)

// ---------------- merged prep kernel (pack_in + border + grid + wt + w2 in ONE launch) ----------------
// [0,8192) pack_in | [8192,8729) zero-border | [8729,8985) grid ch | [8985,13849) conv w (row-major) | [13849,13977) head w
__global__ void k_prep(const float* __restrict__ in1, const float* __restrict__ wc,
                       const float* __restrict__ wl, const float* __restrict__ wm,
                       unsigned short* __restrict__ xp, unsigned short* __restrict__ wt,
                       unsigned short* __restrict__ w2) {
  __shared__ float lt[32][65];
  int bid = blockIdx.x, tid = threadIdx.x;
  if (bid < 8192) {                        // pack_in: interior cells, ch<256
    int cg = bid & 7, y = (bid >> 3) & 63, b = bid >> 9;
    int x = tid & 63, cr = tid >> 6;
#pragma unroll
    for (int i = 0; i < 8; ++i) {
      int cl = i * 4 + cr;
      lt[cl][x] = in1[(((size_t)(b * 256 + cg * 32 + cl) * 64 + y) * 64) + x];
    }
    __syncthreads();
    int xx = tid >> 2, ch = tid & 3;
    u16x8 v;
#pragma unroll
    for (int j = 0; j < 8; ++j) v[j] = f2b(lt[ch * 8 + j][xx]);
    size_t base = ((size_t)((b * 66 + y + 1) * 66 + xx + 1)) * CS + cg * 32 + ch * 8;
    *(u16x8*)(xp + base) = v;
  } else if (bid < 8729) {                 // border cells, all ch
    int idx = (bid - 8192) * 256 + tid;
    if (idx >= 137280) return;
    int cell_i = idx / 33, u = idx - cell_i * 33;
    int b = cell_i / 260, r = cell_i - b * 260;
    int y, x;
    if (r < 66) { y = 0; x = r; }
    else if (r < 132) { y = 65; x = r - 66; }
    else if (r < 196) { y = r - 131; x = 0; }
    else { y = r - 195; x = 65; }
    int cell = (b * 66 + y) * 66 + x;
    *(u32x4*)((unsigned char*)xp + (size_t)cell * (CS * 2) + u * 16) = (u32x4){0u, 0u, 0u, 0u};
  } else if (bid < 8985) {                 // grid channels 256,257 + pad
    int pid = (bid - 8729) * 256 + tid;
    int b = pid >> 12, pi = pid & 4095, y = pi >> 6, x = pi & 63;
    u16x8 v0 = (u16x8){0, 0, 0, 0, 0, 0, 0, 0};
    v0[0] = f2b((float)x); v0[1] = f2b((float)y);
    *(u16x8*)(xp + ((size_t)((b * 66 + y + 1) * 66 + x + 1)) * CS + 256) = v0;
  } else if (bid < 13849) {                // conv weights row-major: wt[o][kpad]
    int idx = (bid - 8985) * 256 + tid;    // 512*2432 = 1245184
    int o = idx / KPAD, k = idx - o * KPAD;
    int dy = k / 800, t = k - dy * 800;
    int dx = t / CS, ci = t - dx * CS;
    float v = (dy < 3 && dx < 3 && ci < 258) ? wc[(size_t)(o * 258 + ci) * 9 + dy * 3 + dx] : 0.f;
    wt[idx] = f2b(v);
  } else {                                 // head weights
    int idx = (bid - 13849) * 256 + tid;
    int o = idx >> 9, k = idx & 511;
    float v = 0.f;
    if (o < 10) v = wl[o * 512 + k];
    else if (o < 58) v = wm[(o - 10) * 512 + k];
    w2[idx] = f2b(v);
  }
}

// ---------------- conv: 256x256 tile, BK=64, rotated 4-window schedule, 3 barriers/tile (R10) ----------------
__global__ __launch_bounds__(512, 2) void k_conv8(const unsigned short* __restrict__ xp,
                                                  const unsigned short* __restrict__ wt,
                                                  unsigned short* __restrict__ cv,
                                                  float* __restrict__ ps) {
  extern __shared__ char smem[];
  int tid = threadIdx.x, lane = tid & 63, wv = tid >> 6;
  int wm = wv >> 2, wn = wv & 3;
  int bid = blockIdx.x;
  int xcd = bid & 7, j = bid >> 3;
  int nt = j & 1;
  int mt = xcd * 32 + (j >> 1);
  int n0 = nt * 256;
  int pix0 = mt * 256;
  int b = pix0 >> 12, pi0 = pix0 & 4095;

  // ---- staging constants ----
  int srow = tid >> 3;
  int ug = (tid & 7) ^ (srow & 7);
  unsigned cellB[4], oB[4];
#pragma unroll
  for (int jj = 0; jj < 4; ++jj) {
    int pi = pi0 + srow + 64 * jj;
    int yy = pi >> 6, xx = pi & 63;
    cellB[jj] = (unsigned)((b * 66 + yy) * 66 + xx) * (CS * 2);
    oB[jj] = (unsigned)(n0 + srow + 64 * jj) * (KPAD * 2);
  }

  auto stageA = [&](int tau, int h) {
    int buf = tau & 1;
    unsigned k = (unsigned)tau * 64u + (unsigned)ug * 8u;
    unsigned dy = k / 800u;
    unsigned t = k - dy * 800u;
    unsigned off = dy * (66u * CS * 2u) + t * 2u;
    const unsigned char* g = (const unsigned char*)xp;
    char* l = smem + buf * 65536 + h * 16384;
    GLOAD16(g + cellB[h * 2] + off, l + tid * 16);
    GLOAD16(g + cellB[h * 2 + 1] + off, l + 8192 + tid * 16);
  };
  auto stageB = [&](int tau, int h) {
    int buf = tau & 1;
    unsigned k2 = ((unsigned)tau * 64u + (unsigned)ug * 8u) * 2u;
    const unsigned char* g = (const unsigned char*)wt;
    char* l = smem + buf * 65536 + 32768 + h * 16384;
    GLOAD16(g + oB[h * 2] + k2, l + tid * 16);
    GLOAD16(g + oB[h * 2 + 1] + k2, l + 8192 + tid * 16);
  };

  // ---- fragment read constants ----
  unsigned aoffb[8], boffb[4];
#pragma unroll
  for (int mf = 0; mf < 8; ++mf) aoffb[mf] = (unsigned)(wm * 128 + mf * 16 + (lane & 15)) * 128u;
#pragma unroll
  for (int nf = 0; nf < 4; ++nf) boffb[nf] = 32768u + (unsigned)(wn * 64 + nf * 16 + (lane & 15)) * 128u;
  int ko = (lane >> 4) & 3, xm = lane & 7;
  unsigned un[2];
#pragma unroll
  for (int kk = 0; kk < 2; ++kk) un[kk] = (unsigned)(((kk * 4 + ko) ^ xm) * 16);

  f32x4 acc[8][4];
#pragma unroll
  for (int i = 0; i < 8; ++i)
#pragma unroll
    for (int jj = 0; jj < 4; ++jj) acc[i][jj] = (f32x4){0.f, 0.f, 0.f, 0.f};

  // ---- prologue: stage tile0 + tile1-B; then pre-read af-lo-k0/bf-k0 of tile0 ----
  stageB(0, 0); stageB(0, 1); stageA(0, 0); stageA(0, 1); stageB(1, 0); stageB(1, 1);
  asm volatile("s_waitcnt vmcnt(4)" ::: "memory");
  __builtin_amdgcn_sched_barrier(0);
  BAR();

  bf16x8 af[4][2], bfr[4][2];
  {
    const char* base0 = smem;
#pragma unroll
    for (int s = 0; s < 4; ++s) af[s][0] = *(const bf16x8*)(base0 + aoffb[s] + un[0]);
#pragma unroll
    for (int s = 0; s < 4; ++s) bfr[s][0] = *(const bf16x8*)(base0 + boffb[s] + un[0]);
  }

#define MM(mi, ni, kk, ab) acc[(ab) + (mi)][(ni)] = \
    __builtin_amdgcn_mfma_f32_16x16x32_bf16(af[(mi)][(kk)], bfr[(ni)][(kk)], acc[(ab) + (mi)][(ni)], 0, 0, 0)

#pragma unroll 1
  for (int tau = 0; tau <= NTILE - 2; ++tau) {   // steady: 0..36
    bool sB = tau < NTILE - 2;
    const char* base = smem + (tau & 1) * 65536;
    const char* nbase = smem + ((tau + 1) & 1) * 65536;
    auto rdA = [&](int s, int kk, int hi) { af[s][kk] = *(const bf16x8*)(base + aoffb[hi * 4 + s] + un[kk]); };
    auto rdB = [&](int s, int kk) { bfr[s][kk] = *(const bf16x8*)(base + boffb[s] + un[kk]); };
    auto rdAn = [&](int s) { af[s][0] = *(const bf16x8*)(nbase + aoffb[s] + un[0]); };
    auto rdBn = [&](int s) { bfr[s][0] = *(const bf16x8*)(nbase + boffb[s] + un[0]); };

    // ---- W0: MFMA m-lo x k0; hide {af-lo-k1, bf-k1}; stageA(+1,0); BAR
    WLG0();
    __builtin_amdgcn_s_setprio(1);
    MM(0, 0, 0, 0); MM(0, 1, 0, 0); rdA(0, 1, 0);
    MM(0, 2, 0, 0); MM(0, 3, 0, 0); rdA(1, 1, 0);
    MM(1, 0, 0, 0); MM(1, 1, 0, 0); rdA(2, 1, 0);
    MM(1, 2, 0, 0); MM(1, 3, 0, 0); rdA(3, 1, 0);
    MM(2, 0, 0, 0); MM(2, 1, 0, 0); rdB(0, 1);
    MM(2, 2, 0, 0); MM(2, 3, 0, 0); rdB(1, 1);
    MM(3, 0, 0, 0); MM(3, 1, 0, 0); rdB(2, 1);
    MM(3, 2, 0, 0); MM(3, 3, 0, 0); rdB(3, 1);
    __builtin_amdgcn_s_setprio(0);
    stageA(tau + 1, 0);
    BAR();

    // ---- W1: MFMA m-lo x k1; hide {af-hi-k0}; stageA(+1,1); BAR
    WLG0();
    __builtin_amdgcn_s_setprio(1);
    MM(0, 0, 1, 0); MM(0, 1, 1, 0); MM(0, 2, 1, 0); MM(0, 3, 1, 0); rdA(0, 0, 1);
    MM(1, 0, 1, 0); MM(1, 1, 1, 0); MM(1, 2, 1, 0); MM(1, 3, 1, 0); rdA(1, 0, 1);
    MM(2, 0, 1, 0); MM(2, 1, 1, 0); MM(2, 2, 1, 0); MM(2, 3, 1, 0); rdA(2, 0, 1);
    MM(3, 0, 1, 0); MM(3, 1, 1, 0); MM(3, 2, 1, 0); MM(3, 3, 1, 0); rdA(3, 0, 1);
    __builtin_amdgcn_s_setprio(0);
    stageA(tau + 1, 1);
    BAR();

    // ---- W2: MFMA m-hi x k0; hide {af-hi-k1}; drain; stageB(+2)/vmcnt; BAR
    WLG0();
    __builtin_amdgcn_s_setprio(1);
    MM(0, 0, 0, 4); MM(0, 1, 0, 4); MM(0, 2, 0, 4); MM(0, 3, 0, 4); rdA(0, 1, 1);
    MM(1, 0, 0, 4); MM(1, 1, 0, 4); MM(1, 2, 0, 4); MM(1, 3, 0, 4); rdA(1, 1, 1);
    MM(2, 0, 0, 4); MM(2, 1, 0, 4); MM(2, 2, 0, 4); MM(2, 3, 0, 4); rdA(2, 1, 1);
    MM(3, 0, 0, 4); MM(3, 1, 0, 4); MM(3, 2, 0, 4); MM(3, 3, 0, 4); rdA(3, 1, 1);
    __builtin_amdgcn_s_setprio(0);
    WLG0();
    if (sB) {
      stageB(tau + 2, 0); stageB(tau + 2, 1);
      asm volatile("s_waitcnt vmcnt(4)" ::: "memory");
      __builtin_amdgcn_sched_barrier(0);
    } else {
      asm volatile("s_waitcnt vmcnt(0)" ::: "memory");
      __builtin_amdgcn_sched_barrier(0);
    }
    BAR();

    // ---- W3: MFMA m-hi x k1; hide NEXT-tile {af-lo-k0, bf-k0} (unconditional); no barrier
    __builtin_amdgcn_s_setprio(1);
    MM(0, 0, 1, 4); MM(0, 1, 1, 4); rdAn(0);
    MM(0, 2, 1, 4); MM(0, 3, 1, 4); rdAn(1);
    MM(1, 0, 1, 4); MM(1, 1, 1, 4); rdAn(2);
    MM(1, 2, 1, 4); MM(1, 3, 1, 4); rdAn(3);
    MM(2, 0, 1, 4); MM(2, 1, 1, 4); rdBn(0);
    MM(2, 2, 1, 4); MM(2, 3, 1, 4); rdBn(1);
    MM(3, 0, 1, 4); MM(3, 1, 1, 4); rdBn(2);
    MM(3, 2, 1, 4); MM(3, 3, 1, 4); rdBn(3);
    __builtin_amdgcn_s_setprio(0);
  }

  // ---- peeled last tile (tau = 37, buf1): no staging, no barriers ----
  {
    const char* base = smem + 65536;
    auto rdA = [&](int s, int kk, int hi) { af[s][kk] = *(const bf16x8*)(base + aoffb[hi * 4 + s] + un[kk]); };
    auto rdB = [&](int s, int kk) { bfr[s][kk] = *(const bf16x8*)(base + boffb[s] + un[kk]); };
    WLG0();
    MM(0, 0, 0, 0); MM(0, 1, 0, 0); rdA(0, 1, 0);
    MM(0, 2, 0, 0); MM(0, 3, 0, 0); rdA(1, 1, 0);
    MM(1, 0, 0, 0); MM(1, 1, 0, 0); rdA(2, 1, 0);
    MM(1, 2, 0, 0); MM(1, 3, 0, 0); rdA(3, 1, 0);
    MM(2, 0, 0, 0); MM(2, 1, 0, 0); rdB(0, 1);
    MM(2, 2, 0, 0); MM(2, 3, 0, 0); rdB(1, 1);
    MM(3, 0, 0, 0); MM(3, 1, 0, 0); rdB(2, 1);
    MM(3, 2, 0, 0); MM(3, 3, 0, 0); rdB(3, 1);
    WLG0();
    MM(0, 0, 1, 0); MM(0, 1, 1, 0); MM(0, 2, 1, 0); MM(0, 3, 1, 0); rdA(0, 0, 1);
    MM(1, 0, 1, 0); MM(1, 1, 1, 0); MM(1, 2, 1, 0); MM(1, 3, 1, 0); rdA(1, 0, 1);
    MM(2, 0, 1, 0); MM(2, 1, 1, 0); MM(2, 2, 1, 0); MM(2, 3, 1, 0); rdA(2, 0, 1);
    MM(3, 0, 1, 0); MM(3, 1, 1, 0); MM(3, 2, 1, 0); MM(3, 3, 1, 0); rdA(3, 0, 1);
    WLG0();
    MM(0, 0, 0, 4); MM(0, 1, 0, 4); MM(0, 2, 0, 4); MM(0, 3, 0, 4); rdA(0, 1, 1);
    MM(1, 0, 0, 4); MM(1, 1, 0, 4); MM(1, 2, 0, 4); MM(1, 3, 0, 4); rdA(1, 1, 1);
    MM(2, 0, 0, 4); MM(2, 1, 0, 4); MM(2, 2, 0, 4); MM(2, 3, 0, 4); rdA(2, 1, 1);
    MM(3, 0, 0, 4); MM(3, 1, 0, 4); MM(3, 2, 0, 4); MM(3, 3, 0, 4); rdA(3, 1, 1);
    WLG0();
    MM(0, 0, 1, 4); MM(0, 1, 1, 4); MM(0, 2, 1, 4); MM(0, 3, 1, 4);
    MM(1, 0, 1, 4); MM(1, 1, 1, 4); MM(1, 2, 1, 4); MM(1, 3, 1, 4);
    MM(2, 0, 1, 4); MM(2, 1, 1, 4); MM(2, 2, 1, 4); MM(2, 3, 1, 4);
    MM(3, 0, 1, 4); MM(3, 1, 1, 4); MM(3, 2, 1, 4); MM(3, 3, 1, 4);
  }
#undef MM

  __syncthreads();  // all waves done before epilogue overwrites smem

  // ---- epilogue 1: raw conv -> cv (bf16), via LDS repack (XOR-4 store swizzle) ----
  unsigned short* l16 = (unsigned short*)smem;
#pragma unroll
  for (int mf = 0; mf < 8; ++mf)
#pragma unroll
    for (int nf = 0; nf < 4; ++nf)
#pragma unroll
      for (int r = 0; r < 4; ++r) {
        int row = wm * 128 + mf * 16 + (lane >> 4) * 4 + r;
        int col = wn * 64 + nf * 16 + (lane & 15);
        int colx = col ^ (((row >> 2) & 3) << 3);
        l16[row * 256 + colx] = f2b(acc[mf][nf][r]);
      }
  __syncthreads();
#pragma unroll
  for (int i = 0; i < 16; ++i) {
    int q = tid + 512 * i;
    int prow = q >> 5, c16 = q & 31;
    int c16g = c16 ^ ((prow >> 2) & 3);
    *(u16x8*)(cv + ((size_t)(pix0 + prow) * 512 + n0 + c16g * 8)) = *(const u16x8*)(l16 + q * 8);
  }
  __syncthreads();

  // ---- epilogue 2: BN partial stats from f32 acc ----
  float* lf = (float*)smem;
  float sv[4], qv[4];
#pragma unroll
  for (int nf = 0; nf < 4; ++nf) {
    float s = 0.f, q = 0.f;
#pragma unroll
    for (int mf = 0; mf < 8; ++mf)
#pragma unroll
      for (int r = 0; r < 4; ++r) { float v = acc[mf][nf][r]; s += v; q += v * v; }
    s += __shfl_xor(s, 16); s += __shfl_xor(s, 32);
    q += __shfl_xor(q, 16); q += __shfl_xor(q, 32);
    sv[nf] = s; qv[nf] = q;
  }
  if (lane < 16) {
#pragma unroll
    for (int nf = 0; nf < 4; ++nf) {
      int ch = wn * 64 + nf * 16 + lane;
      lf[wm * 256 + ch] = sv[nf];
      lf[512 + wm * 256 + ch] = qv[nf];
    }
  }
  __syncthreads();
  if (tid < 256) {
    float S = lf[tid] + lf[256 + tid];
    float Q = lf[512 + tid] + lf[768 + tid];
    ((float2*)ps)[(size_t)(n0 + tid) * 256 + mt] = make_float2(S, Q);
  }
}

// ---------------- BN finalize: scale/bias (16 blocks, shfl-reduced) ----------------
__global__ void k_bnfinal(const float* __restrict__ ps, const float* __restrict__ gamma,
                          const float* __restrict__ beta, float* __restrict__ sb) {
  int c = blockIdx.x * 32 + (threadIdx.x >> 3);
  int sl = threadIdx.x & 7;
  const float2* p2 = (const float2*)ps + (size_t)c * 256 + sl * 32;
  float s = 0.f, q = 0.f;
#pragma unroll 8
  for (int i = 0; i < 32; ++i) { float2 v = p2[i]; s += v.x; q += v.y; }
  s += __shfl_xor(s, 1); s += __shfl_xor(s, 2); s += __shfl_xor(s, 4);
  q += __shfl_xor(q, 1); q += __shfl_xor(q, 2); q += __shfl_xor(q, 4);
  if (sl == 0) {
    float mean = s * (1.0f / 65536.0f);
    float var = q * (1.0f / 65536.0f) - mean * mean;
    float sc = gamma[c] / sqrtf(var + 1e-5f);
    sb[c] = sc;
    sb[512 + c] = beta[c] - mean * sc;
  }
}

// ---------------- head: BN+leaky fused A-load, 256px x 64out GEMM (K=512) + decode ----------------
__global__ __launch_bounds__(256) void k_head(const unsigned short* __restrict__ cv,
                                              const unsigned short* __restrict__ w2,
                                              const float* __restrict__ bl,
                                              const float* __restrict__ bm,
                                              const float* __restrict__ sb,
                                              float* __restrict__ out) {
  __shared__ float lo[256][59];
  __shared__ float sS[512], sBb[512];
  int tid = threadIdx.x, lane = tid & 63, wv = tid >> 6;
  int pix0 = blockIdx.x * 256;
  sS[tid] = sb[tid]; sS[256 + tid] = sb[256 + tid];
  sBb[tid] = sb[512 + tid]; sBb[256 + tid] = sb[768 + tid];
  __syncthreads();

  f32x4 acc[4][4];
#pragma unroll
  for (int mf = 0; mf < 4; ++mf)
#pragma unroll
    for (int nf = 0; nf < 4; ++nf) acc[mf][nf] = (f32x4){0.f, 0.f, 0.f, 0.f};
  int ko = lane >> 4;

  for (int k0 = 0; k0 < 512; k0 += 32) {
    int c0 = k0 + ko * 8;
    f32x4 sc0 = *(const f32x4*)&sS[c0], sc1 = *(const f32x4*)&sS[c0 + 4];
    f32x4 bo0 = *(const f32x4*)&sBb[c0], bo1 = *(const f32x4*)&sBb[c0 + 4];
    bf16x8 a[4], bg[4];
#pragma unroll
    for (int f = 0; f < 4; ++f) {
      bg[f] = *(const bf16x8*)(w2 + (size_t)(f * 16 + (lane & 15)) * 512 + c0);
      u16x8 raw = *(const u16x8*)(cv + (size_t)(pix0 + wv * 64 + f * 16 + (lane & 15)) * 512 + c0);
      u16x8 av;
#pragma unroll
      for (int jj = 0; jj < 4; ++jj) {
        float v = b2f(raw[jj]) * sc0[jj] + bo0[jj];
        v = (v > 0.f) ? v : 0.1f * v;
        av[jj] = f2b(v);
      }
#pragma unroll
      for (int jj = 0; jj < 4; ++jj) {
        float v = b2f(raw[4 + jj]) * sc1[jj] + bo1[jj];
        v = (v > 0.f) ? v : 0.1f * v;
        av[4 + jj] = f2b(v);
      }
      a[f] = __builtin_bit_cast(bf16x8, av);
    }
#pragma unroll
    for (int mf = 0; mf < 4; ++mf)
#pragma unroll
      for (int nf = 0; nf < 4; ++nf)
        acc[mf][nf] = __builtin_amdgcn_mfma_f32_16x16x32_bf16(a[mf], bg[nf], acc[mf][nf], 0, 0, 0);
  }

  float bias[4]; int colv[4];
#pragma unroll
  for (int nf = 0; nf < 4; ++nf) {
    int col = nf * 16 + (lane & 15);
    colv[nf] = col;
    bias[nf] = (col < 10) ? bl[col] : ((col < 58) ? bm[col - 10] : 0.f);
  }
#pragma unroll
  for (int mf = 0; mf < 4; ++mf)
#pragma unroll
    for (int nf = 0; nf < 4; ++nf)
#pragma unroll
      for (int r = 0; r < 4; ++r) {
        int row = wv * 64 + mf * 16 + (lane >> 4) * 4 + r;
        if (colv[nf] < 58) lo[row][colv[nf]] = acc[mf][nf][r] + bias[nf];
      }
  __syncthreads();

  // ---- decode: one thread = one pixel ----
  int pix = pix0 + tid;
  int b = pix >> 12, pi = pix & 4095;
  int yi = pi >> 6, xi = pi & 63;
  float X = (float)xi, Y = (float)yi;
  const float* O = lo[tid];

  float* outP = out;
  float* outB = out + 655360;
  float* outOL = out + 1572864;
  float* outOC = out + 2752512;
  float* outML = out + 3932160;
  float* outMC = out + 4521984;
  float* outWC = out + 5111808;
  float* outOD = out + 5636096;

  float pr[10];
#pragma unroll
  for (int i = 0; i < 10; ++i) { pr[i] = O[i]; outP[(size_t)pix * 10 + i] = pr[i]; }
  const float st = 8.f, ist = 0.125f;
  float l0 = pr[0] * pr[0] * st, l1 = pr[1] * pr[1] * st;
  float l2 = pr[2] * pr[2] * st, l3 = pr[3] * pr[3] * st;
  float cx = X * st + 4.f, cy = Y * st + 4.f;
  float xmin = cx - l3, ymin = cy - l0, xmax = cx + l1, ymax = cy + l2;
  float w = l1 + l3, h = l0 + l2;
  float xc = 0.5f * (xmax + xmin), yc = 0.5f * (ymax + ymin);
  float r = sigf(pr[8]);
  float maskr = (r > 0.9f) ? 0.f : 1.f;
  float s0 = sigf(pr[4]) * maskr, s1 = sigf(pr[5]) * maskr;
  float s2 = sigf(pr[6]) * maskr, s3 = sigf(pr[7]) * maskr;
  float conf = sigf(pr[9]);
  {
    size_t bo = (size_t)pix * 14;
    outB[bo + 0] = xc; outB[bo + 1] = yc; outB[bo + 2] = w; outB[bo + 3] = h;
    outB[bo + 4] = s0; outB[bo + 5] = s1; outB[bo + 6] = s2; outB[bo + 7] = s3;
    outB[bo + 8] = r;  outB[bo + 9] = l0; outB[bo + 10] = l1; outB[bo + 11] = l2;
    outB[bo + 12] = l3; outB[bo + 13] = conf;
  }
  float x1 = xmin + s0 * w, x7 = xmax - s2 * w;
  float y5 = ymin + s1 * h, y3 = ymax - s3 * h;
  float xob = 0.5f * (x1 + x7), yob = 0.5f * (y5 + y3);
  float ov[22];
#pragma unroll
  for (int jj = 0; jj < 22; ++jj) ov[jj] = sigf(O[28 + jj]);
  float eps = ceilf(0.01f * w);
  bool c0 = x1 < xmin + eps;
  float xp0 = c0 ? x1 : xmin + ov[0] * (x1 - xmin);
  float yp0 = c0 ? ymin + ov[0] * (y3 - ymin)
                 : (y3 - ymin) / (xmin - x1 + 1e-8f) * (xp0 - x1) + ymin;
  bool c2 = x1 > xmax - eps;
  float xp2 = c2 ? x1 : xmax - ov[1] * (xmax - x1);
  float yp2 = c2 ? ymin + ov[1] * (y5 - ymin)
                 : (y5 - ymin) / (xmax - x1 + 1e-8f) * (xp2 - x1) + ymin;
  bool c6 = x7 < xmin + eps;
  float xp6 = c6 ? x7 : xmin + ov[2] * (x7 - xmin);
  float yp6 = c6 ? ymax - ov[2] * (ymax - y3)
                 : (y3 - ymax) / (xmin - x7 + 1e-8f) * (xp6 - x7) + ymax;
  bool c8c = x7 > xmax - eps;
  float xp8 = c8c ? x7 : xmax - ov[3] * (xmax - x7);
  float yp8 = c8c ? ymax - ov[3] * (ymax - y5)
                  : (y5 - ymax) / (xmax - x7 + 1e-8f) * (xp8 - x7) + ymax;

  size_t olb = ((size_t)b * 18) * 4096 + pi;
  outOL[olb + 0 * 4096] = yp0 * ist + 1.f - Y;
  outOL[olb + 1 * 4096] = xp0 * ist + 1.f - X;
  outOL[olb + 2 * 4096] = ymin * ist + 1.f - Y;
  outOL[olb + 3 * 4096] = x1 * ist - X;
  outOL[olb + 4 * 4096] = yp2 * ist + 1.f - Y;
  outOL[olb + 5 * 4096] = xp2 * ist - 1.f - X;
  outOL[olb + 6 * 4096] = y3 * ist - Y;
  outOL[olb + 7 * 4096] = xmin * ist + 1.f - X;
  outOL[olb + 8 * 4096] = 0.f;
  outOL[olb + 9 * 4096] = 0.f;
  outOL[olb + 10 * 4096] = y5 * ist - Y;
  outOL[olb + 11 * 4096] = xmax * ist - 1.f - X;
  outOL[olb + 12 * 4096] = yp6 * ist - 1.f - Y;
  outOL[olb + 13 * 4096] = xp6 * ist + 1.f - X;
  outOL[olb + 14 * 4096] = ymax * ist - 1.f - Y;
  outOL[olb + 15 * 4096] = x7 * ist - X;
  outOL[olb + 16 * 4096] = yp8 * ist - 1.f - Y;
  outOL[olb + 17 * 4096] = xp8 * ist - 1.f - X;

  float A1 = x1 - xmax, B1 = ymin - y5, A2 = xmin - x7, B2 = y3 - ymax;
  float width = 0.5f * (sqrtf(A1 * A1 + B1 * B1) + sqrtf(A2 * A2 + B2 * B2));
  float C1 = xmin - x1, D1 = y3 - ymin, C2 = x7 - xmax, D2 = ymax - y5;
  float height = 0.5f * (sqrtf(C1 * C1 + D1 * D1) + sqrtf(C2 * C2 + D2 * D2));
  float ang = 0.5f * (atanf((y5 - ymin) / (xmax - x1 + 1e-4f)) +
                      atanf((ymax - y3) / (x7 - xmin + 1e-4f)));
  float ca = cosf(ang), sa = sinf(ang);
  const float DD = 0.70710678118654752f;
  const float dyc[9] = {DD, 1.f, DD, 0.f, 0.f, 0.f, -DD, -1.f, -DD};
  const float dxc[9] = {DD, 0.f, -DD, 1.f, 0.f, -1.f, DD, 0.f, -DD};
  size_t ocb = ((size_t)b * 18) * 4096 + pi;
  size_t odb = (size_t)pix * 18;
#pragma unroll
  for (int k = 0; k < 9; ++k) {
    float xd = xob - 0.5f * width + ov[13 + k] * width;
    float yd = yob - 0.5f * height + ov[4 + k] * height;
    float ddx = xd - xob, ddy = yd - yob;
    float xd0 = ca * ddx - sa * ddy + xob;
    float xdc = fminf(fmaxf(xd0, xmin), xmax);
    float yd0 = sa * ddx + ca * ddy + yob;
    float ydc = fminf(fmaxf(yd0, ymin), ymax);
    outOC[ocb + (size_t)(2 * k) * 4096] = ydc * ist + dyc[k] - Y;
    outOC[ocb + (size_t)(2 * k + 1) * 4096] = xdc * ist + dxc[k] - X;
    outOD[odb + k] = xdc;
    outOD[odb + 9 + k] = ydc;
  }
  size_t mlb = ((size_t)b * 9) * 4096 + pi;
#pragma unroll
  for (int k = 0; k < 9; ++k) outML[mlb + (size_t)k * 4096] = sigf(O[10 + k]);
#pragma unroll
  for (int k = 0; k < 9; ++k) outMC[mlb + (size_t)k * 4096] = sigf(O[19 + k]);
  float v8[8], mx = -1e30f;
#pragma unroll
  for (int k = 0; k < 8; ++k) { v8[k] = O[50 + k]; mx = fmaxf(mx, v8[k]); }
  float sm = 0.f;
#pragma unroll
  for (int k = 0; k < 8; ++k) { v8[k] = __expf(v8[k] - mx); sm += v8[k]; }
  float inv = 1.f / sm;
  size_t wcb = ((size_t)b * 8) * 4096 + pi;
#pragma unroll
  for (int k = 0; k < 8; ++k) outWC[wcb + (size_t)k * 4096] = v8[k] * inv;
}

// ---------------- launch ----------------
extern "C" void kernel_launch(void* const* d_in, const int* in_sizes, int n_in,
                              void* d_out, int out_size, void* d_ws, size_t ws_size,
                              hipStream_t stream) {
  const float* in1 = (const float*)d_in[0];
  const float* wconv = (const float*)d_in[1];
  const float* gamma = (const float*)d_in[2];
  const float* beta = (const float*)d_in[3];
  const float* wloc = (const float*)d_in[4];
  const float* bloc = (const float*)d_in[5];
  const float* wmask = (const float*)d_in[6];
  const float* bmask = (const float*)d_in[7];
  unsigned char* ws = (unsigned char*)d_ws;
  unsigned short* xp = (unsigned short*)(ws + XP_OFF);
  unsigned short* wt = (unsigned short*)(ws + WT_OFF);
  unsigned short* w2 = (unsigned short*)(ws + W2_OFF);
  unsigned short* cv = (unsigned short*)(ws + CV_OFF);
  float* ps = (float*)(ws + PS_OFF);
  float* sb = (float*)(ws + SB_OFF);
  float* out = (float*)d_out;

  (void)hipFuncSetAttribute(reinterpret_cast<const void*>(k_conv8),
                            hipFuncAttributeMaxDynamicSharedMemorySize, 131072);

  k_prep<<<dim3(13977), dim3(256), 0, stream>>>(in1, wconv, wloc, wmask, xp, wt, w2);
  k_conv8<<<dim3(512), dim3(512), 131072, stream>>>(xp, wt, cv, ps);
  k_bnfinal<<<dim3(16), dim3(256), 0, stream>>>(ps, gamma, beta, sb);
  k_head<<<dim3(256), dim3(256), 0, stream>>>(cv, w2, bloc, bmask, sb, out);
}